// Round 4
// baseline (480.517 us; speedup 1.0000x reference)
//
#include <hip/hip_runtime.h>

typedef _Float16 half8 __attribute__((ext_vector_type(8)));
typedef float floatx4 __attribute__((ext_vector_type(4)));

#define AS1 __attribute__((address_space(1)))
#define AS3 __attribute__((address_space(3)))

// ---------------------------------------------------------------------------
// W transpose + fp32->fp16: W [1024][1024] (k,n) -> Wt [1024][1024] (n,k)
// ---------------------------------------------------------------------------
__global__ __launch_bounds__(256) void wtrans_kernel(
    const float* __restrict__ W0, const float* __restrict__ W1,
    const float* __restrict__ W2, _Float16* __restrict__ Wt)
{
    __shared__ _Float16 t[64 * 72];
    const float* W = (blockIdx.z == 0) ? W0 : (blockIdx.z == 1) ? W1 : W2;
    _Float16* O = Wt + (long)blockIdx.z * 1048576;
    const int tid = threadIdx.x;
    const int kb = blockIdx.y * 64, nb = blockIdx.x * 64;
#pragma unroll
    for (int i = 0; i < 4; i++) {
        int r = (tid >> 4) + i * 16;
        int c = (tid & 15) * 4;
        floatx4 w = *(const floatx4*)&W[(long)(kb + r) * 1024 + nb + c];
#pragma unroll
        for (int j = 0; j < 4; j++) t[(c + j) * 72 + r] = (_Float16)w[j];
    }
    __syncthreads();
    const int c = tid >> 2, rch = (tid & 3) * 16;
    half8 v0 = *(const half8*)&t[c * 72 + rch];
    half8 v1 = *(const half8*)&t[c * 72 + rch + 8];
    _Float16* o = &O[(long)(nb + c) * 1024 + kb + rch];
    *(half8*)o = v0;
    *(half8*)(o + 8) = v1;
}

// ---------------------------------------------------------------------------
// fp32 -> fp16 cast, 8 elems/thread, grid-stride
// ---------------------------------------------------------------------------
__global__ __launch_bounds__(256) void f32_to_f16_kernel(
    const float* __restrict__ in, _Float16* __restrict__ out, int n)
{
    for (long i = ((long)blockIdx.x * 256 + threadIdx.x) * 8; i < n;
         i += (long)gridDim.x * 256 * 8) {
        floatx4 a = *(const floatx4*)&in[i];
        floatx4 b = *(const floatx4*)&in[i + 4];
        half8 h;
#pragma unroll
        for (int e = 0; e < 4; e++) { h[e] = (_Float16)a[e]; h[e + 4] = (_Float16)b[e]; }
        *(half8*)&out[i] = h;
    }
}

// ---------------------------------------------------------------------------
// m97-style GEMM, BK=64 (two BK=32 slabs per barrier pair, 32 MFMA/barrier).
// C[m][n] = sum_k A[m][k] * Bt[n][k]   (both fp16 row-major)
// 128x128 tile, 256 threads (4 waves, 4x4 16x16x32 MFMAs each).
//
// XCD swizzle: bid&7 = XCD, bid>>3 = slot -> each XCD owns a contiguous
// (z, y-slab) region; B panels stay L2-resident per XCD.
//
// LDS bank swizzle: staging thread (r, c2=tid&3) loads global col-group
// c2 ^ ((r>>1)&3); fragment reads slot quad ^ ((lr>>1)&3). Bank-group of a
// b128 read = 4*(lr&1) + (quad ^ ((lr>>1)&3)) -> 8 distinct groups per
// 8-lane phase -> conflict-free (was 4-way, 8.4M SQ_LDS_BANK_CONFLICT).
//
// MODE 0: fp16 out row-major, (+bias per z)     (projQ/K fused)
// MODE 1: fp16 out TRANSPOSED per batch (+bias) (projV -> Vt [d][t])
// MODE 2: fp32 out row-major, * 1/R[row]        (PV -> d_out)
// MODE 3: fp16 out = exp(acc*scale), atomic row sums into R  (scores)
// ---------------------------------------------------------------------------
template <int MODE>
__global__ __launch_bounds__(256) void gemm128_kernel(
    const _Float16* __restrict__ A, const _Float16* __restrict__ Bt,
    void* __restrict__ Cv, const float* __restrict__ bias,
    const float* __restrict__ bias2, float* __restrict__ R,
    int nx, int ny,
    int K, int lda, int ldb, int ldc,
    long aBatch, long bBatch, long cBatch, float scale)
{
    constexpr int SMEM_ELEMS = (MODE == 1) ? 17408 : 16384;
    __shared__ _Float16 smem[SMEM_ELEMS];
    _Float16* Ash = smem;
    _Float16* Bsh = smem + 8192;

    const int tid = threadIdx.x;
    const int wave = tid >> 6, lane = tid & 63;
    const int quad = lane >> 4, lr = lane & 15;
    const int wm = wave & 1, wn = wave >> 1;

    // ---- XCD swizzle ----
    const int P = gridDim.x >> 3;                 // blocks per XCD
    const int g = (blockIdx.x & 7) * P + (blockIdx.x >> 3);
    const int pplane = nx * ny;
    const int z = g / pplane;
    const int rr = g - z * pplane;
    const int by = rr / nx;
    const int bx = rr - by * nx;
    const int m0 = by * 128, n0 = bx * 128;

    const _Float16* Ab = A + (long)z * aBatch;
    const _Float16* Bb = Bt + (long)z * bBatch;

    // staging: thread tid loads 16B; LDS dst tid*8 (HW: wave base + lane*16B)
    const int srow = tid >> 2;                              // 0..63
    const int scol = ((tid & 3) ^ ((srow >> 1) & 3)) * 8;   // bank swizzle
    const long ag0 = (long)(m0 + srow) * lda + scol;
    const long bg0 = (long)(n0 + srow) * ldb + scol;
    const int sdst = tid * 8;

    floatx4 acc[4][4] = {};

    for (int k0 = 0; k0 < K; k0 += 64) {
#pragma unroll
        for (int s = 0; s < 2; s++) {
            const int kk = k0 + s * 32;
            const int so = s * 4096;
            __builtin_amdgcn_global_load_lds(
                (AS1 void*)(Ab + ag0 + kk), (AS3 void*)(Ash + so + sdst), 16, 0, 0);
            __builtin_amdgcn_global_load_lds(
                (AS1 void*)(Ab + ag0 + (long)64 * lda + kk), (AS3 void*)(Ash + so + sdst + 2048), 16, 0, 0);
            __builtin_amdgcn_global_load_lds(
                (AS1 void*)(Bb + bg0 + kk), (AS3 void*)(Bsh + so + sdst), 16, 0, 0);
            __builtin_amdgcn_global_load_lds(
                (AS1 void*)(Bb + bg0 + (long)64 * ldb + kk), (AS3 void*)(Bsh + so + sdst + 2048), 16, 0, 0);
        }
        __syncthreads();

        const int slotA = (quad ^ ((lr >> 1) & 3)) * 8;
#pragma unroll
        for (int s = 0; s < 2; s++) {
            const int so = s * 4096;
            half8 aF[4], bF[4];
#pragma unroll
            for (int i = 0; i < 4; i++) {
                aF[i] = *(const half8*)&Ash[so + (wm * 64 + i * 16 + lr) * 32 + slotA];
                bF[i] = *(const half8*)&Bsh[so + (wn * 64 + i * 16 + lr) * 32 + slotA];
            }
#pragma unroll
            for (int mi = 0; mi < 4; mi++)
#pragma unroll
                for (int ni = 0; ni < 4; ni++)
                    acc[mi][ni] = __builtin_amdgcn_mfma_f32_16x16x32_f16(
                        aF[mi], bF[ni], acc[mi][ni], 0, 0, 0);
        }
        __syncthreads();
    }

    // ---- epilogue ----  C/D frag: m = quad*4+reg, n = lane&15
    if constexpr (MODE == 0) {
        _Float16* C = (_Float16*)Cv + (long)z * cBatch;
        const float* bz = (z == 0 || !bias2) ? bias : bias2;
#pragma unroll
        for (int ni = 0; ni < 4; ni++) {
            const int n = n0 + wn * 64 + ni * 16 + lr;
            const float bv_ = bz ? bz[n] : 0.0f;
#pragma unroll
            for (int mi = 0; mi < 4; mi++) {
                const int mb = m0 + wm * 64 + mi * 16 + quad * 4;
#pragma unroll
                for (int r = 0; r < 4; r++)
                    C[(long)(mb + r) * ldc + n] = (_Float16)(acc[mi][ni][r] + bv_);
            }
        }
    } else if constexpr (MODE == 1) {
        _Float16* ctile = smem;
#pragma unroll
        for (int ni = 0; ni < 4; ni++) {
            const int nl = wn * 64 + ni * 16 + lr;
            const float bv_ = bias ? bias[n0 + nl] : 0.0f;
#pragma unroll
            for (int mi = 0; mi < 4; mi++) {
                const int ml = wm * 64 + mi * 16 + quad * 4;
#pragma unroll
                for (int r = 0; r < 4; r++)
                    ctile[nl * 136 + ml + r] = (_Float16)(acc[mi][ni][r] + bv_);
            }
        }
        __syncthreads();
        _Float16* C = (_Float16*)Cv + (long)(m0 >> 11) * cBatch;  // batch from m
        const int t0 = m0 & 2047;
#pragma unroll
        for (int p = 0; p < 8; p++) {
            const int row = p * 16 + (tid >> 4);
            const int seg = (tid & 15) * 8;
            half8 v = *(const half8*)&ctile[row * 136 + seg];
            *(half8*)&C[(long)(n0 + row) * ldc + t0 + seg] = v;
        }
    } else if constexpr (MODE == 2) {
        float* C = (float*)Cv + (long)z * cBatch;
        const float* Rz = R + (long)z * 2048;
        float inv[4][4];
#pragma unroll
        for (int mi = 0; mi < 4; mi++) {
            const int mb = m0 + wm * 64 + mi * 16 + quad * 4;
#pragma unroll
            for (int r = 0; r < 4; r++) inv[mi][r] = 1.0f / Rz[mb + r];
        }
#pragma unroll
        for (int ni = 0; ni < 4; ni++) {
            const int n = n0 + wn * 64 + ni * 16 + lr;
#pragma unroll
            for (int mi = 0; mi < 4; mi++) {
                const int mb = m0 + wm * 64 + mi * 16 + quad * 4;
#pragma unroll
                for (int r = 0; r < 4; r++)
                    C[(long)(mb + r) * ldc + n] = acc[mi][ni][r] * inv[mi][r];
            }
        }
    } else {  // MODE 3: scores -> E = exp(acc*scale), row sums into R
        _Float16* C = (_Float16*)Cv + (long)z * cBatch;
        float* Rz = R + (long)z * 2048;
        float rs[4][4] = {};
#pragma unroll
        for (int ni = 0; ni < 4; ni++) {
            const int n = n0 + wn * 64 + ni * 16 + lr;
#pragma unroll
            for (int mi = 0; mi < 4; mi++) {
                const int mb = m0 + wm * 64 + mi * 16 + quad * 4;
#pragma unroll
                for (int r = 0; r < 4; r++) {
                    float e = __expf(acc[mi][ni][r] * scale);
                    C[(long)(mb + r) * ldc + n] = (_Float16)e;
                    rs[mi][r] += e;
                }
            }
        }
        // reduce across the 16 lr-lanes of each quad (lr = lane bits 0-3)
#pragma unroll
        for (int off = 1; off < 16; off <<= 1)
#pragma unroll
            for (int mi = 0; mi < 4; mi++)
#pragma unroll
                for (int r = 0; r < 4; r++)
                    rs[mi][r] += __shfl_xor(rs[mi][r], off, 64);
        if (lr == 0) {
#pragma unroll
            for (int mi = 0; mi < 4; mi++) {
                const int mb = m0 + wm * 64 + mi * 16 + quad * 4;
#pragma unroll
                for (int r = 0; r < 4; r++)
                    atomicAdd(&Rz[mb + r], rs[mi][r]);
            }
        }
    }
}

// ---------------------------------------------------------------------------
// B=8, S=2048, D=1024.  Workspace layout (bytes):
//   Q   fp16 [16384][1024]            @ 0          (33,554,432)
//   Kb  fp16 [16384][1024]            @ 33,554,432 (33,554,432)
//   Vt  fp16 [8][1024][2048]          @ 67,108,864 (33,554,432)
//   Sc  fp16 [8][2048][2048]          @ 100,663,296 (67,108,864)  (xb aliased)
//   Wt  fp16 [3][1024][1024]          @ 167,772,160 (6,291,456)
//   R   fp32 [8][2048]                @ 174,063,616 (65,536)
// total 174,129,152
// ---------------------------------------------------------------------------
extern "C" void kernel_launch(void* const* d_in, const int* in_sizes, int n_in,
                              void* d_out, int out_size, void* d_ws, size_t ws_size,
                              hipStream_t stream)
{
    const float* x  = (const float*)d_in[0];
    const float* Wq = (const float*)d_in[1];
    const float* bq = (const float*)d_in[2];
    const float* Wk = (const float*)d_in[3];
    const float* bk = (const float*)d_in[4];
    const float* Wv = (const float*)d_in[5];
    const float* bv = (const float*)d_in[6];

    if (ws_size < 174129152u) return;  // cannot run

    char* ws = (char*)d_ws;
    _Float16* Q  = (_Float16*)(ws + 0);
    _Float16* Vt = (_Float16*)(ws + 67108864);
    _Float16* Sc = (_Float16*)(ws + 100663296);
    _Float16* Wt = (_Float16*)(ws + 167772160);
    float*    R  = (float*)(ws + 174063616);
    _Float16* xb = Sc;  // aliased: xb dead before Sc is written
    _Float16* Kb = Q + 16777216;
    float* out = (float*)d_out;

    hipMemsetAsync(R, 0, 65536, stream);
    wtrans_kernel<<<dim3(16, 16, 3), 256, 0, stream>>>(Wq, Wk, Wv, Wt);
    f32_to_f16_kernel<<<2048, 256, 0, stream>>>(x, xb, 16777216);

    // Q and K projections fused via z: M=16384, N=1024, K=1024, 2048 blocks
    gemm128_kernel<0><<<2048, 256, 0, stream>>>(
        xb, Wt, Q, bq, bk, nullptr, 8, 128, 1024, 1024, 1024, 1024,
        0, 1048576, 16777216, 1.0f);
    // V projection -> Vt [b][d][t], 1024 blocks
    gemm128_kernel<1><<<1024, 256, 0, stream>>>(
        xb, Wt + 2097152, Vt, bv, nullptr, nullptr, 8, 128, 1024, 1024, 1024, 2048,
        0, 0, 2097152, 1.0f);

    // scores: E = exp(QK^T/32), row sums -> R. per-batch M=N=2048, K=1024
    gemm128_kernel<3><<<2048, 256, 0, stream>>>(
        Q, Kb, Sc, nullptr, nullptr, R, 16, 16, 1024, 1024, 1024, 2048,
        2097152, 2097152, 4194304, 0.03125f);

    // out = (E V) / R : per-batch M=2048, N=1024, K=2048
    gemm128_kernel<2><<<1024, 256, 0, stream>>>(
        Sc, Vt, out, nullptr, nullptr, R, 8, 16, 2048, 2048, 2048, 1024,
        4194304, 2097152, 2097152, 1.0f);
}